// Round 3
// baseline (1669.054 us; speedup 1.0000x reference)
//
#include <hip/hip_runtime.h>
#include <hip/hip_bf16.h>
#include <stdint.h>

#define LQ 2048
#define DM 1024
#define NH 16
#define HD 64
#define NPAIR 32
#define SCALE_F 0.125f

// ---------------- Q projections: Qa = rope(x@wq_attn), Qr = x@wq_rel ----------------
// inputs f32. Each block: 16 rows of x, one weight matrix (m), one half of its columns.
#define QROWS 16
__global__ __launch_bounds__(256) void k_proj_q(
    const float* __restrict__ x, const float* __restrict__ wqa, const float* __restrict__ wqr,
    const float* __restrict__ fcos, const float* __restrict__ fsin,
    float* __restrict__ Qa, float* __restrict__ Qr)
{
    __shared__ float xS[QROWS * DM];   // 64 KB
    const int bid = blockIdx.x;
    const int i0 = (bid >> 2) * QROWS;
    const int m = (bid >> 1) & 1;      // 0: attn (rope), 1: rel
    const int half = bid & 1;
    const int tid = threadIdx.x;
    {
        const float4* src = (const float4*)(x + (size_t)i0 * DM);
        float4* dst4 = (float4*)xS;
        for (int t = tid; t < QROWS * DM / 4; t += 256) dst4[t] = src[t];
    }
    __syncthreads();
    const int q = half * 256 + tid;    // global pair index 0..511, cols 2q, 2q+1
    const float2* __restrict__ w2 = (const float2*)(m ? wqr : wqa);  // 512 pairs per row
    float ae[QROWS], ao[QROWS];
#pragma unroll
    for (int r = 0; r < QROWS; ++r) { ae[r] = 0.f; ao[r] = 0.f; }
    for (int k = 0; k < DM; k += 4) {
        float2 w0 = w2[(size_t)(k + 0) * (DM / 2) + q];
        float2 w1 = w2[(size_t)(k + 1) * (DM / 2) + q];
        float2 w2v = w2[(size_t)(k + 2) * (DM / 2) + q];
        float2 w3 = w2[(size_t)(k + 3) * (DM / 2) + q];
#pragma unroll
        for (int r = 0; r < QROWS; ++r) {
            float4 xv = *(const float4*)&xS[r * DM + k];
            ae[r] = fmaf(xv.x, w0.x, ae[r]);  ao[r] = fmaf(xv.x, w0.y, ao[r]);
            ae[r] = fmaf(xv.y, w1.x, ae[r]);  ao[r] = fmaf(xv.y, w1.y, ao[r]);
            ae[r] = fmaf(xv.z, w2v.x, ae[r]); ao[r] = fmaf(xv.z, w2v.y, ao[r]);
            ae[r] = fmaf(xv.w, w3.x, ae[r]);  ao[r] = fmaf(xv.w, w3.y, ao[r]);
        }
    }
    float* __restrict__ dst = m ? Qr : Qa;
    const int p = q & (NPAIR - 1);
#pragma unroll
    for (int r = 0; r < QROWS; ++r) {
        float oe = ae[r], oo = ao[r];
        if (m == 0) {
            float c = fcos[(i0 + r) * NPAIR + p];
            float s = fsin[(i0 + r) * NPAIR + p];
            oe = ae[r] * c - ao[r] * s;
            oo = ae[r] * s + ao[r] * c;
        }
        *(float2*)&dst[(size_t)(i0 + r) * DM + 2 * q] = make_float2(oe, oo);
    }
}

// ---------------- KV projections: Ka = rope(x@wk_attn), Kr = x@wk_rel, SV = symbols@wv ----
#define KVROWS 8
__global__ __launch_bounds__(128) void k_proj_kv(
    const float* __restrict__ x, const float* __restrict__ symbols,
    const float* __restrict__ wka, const float* __restrict__ wkr, const float* __restrict__ wv,
    const float* __restrict__ fcos, const float* __restrict__ fsin,
    float* __restrict__ Ka, float* __restrict__ Kr, float* __restrict__ SV)
{
    __shared__ float xS[KVROWS * DM], sS[KVROWS * DM];   // 32KB + 32KB
    const int i0 = blockIdx.x * KVROWS;
    const int tid = threadIdx.x;
    {
        const float4* sx = (const float4*)(x + (size_t)i0 * DM);
        const float4* ss = (const float4*)(symbols + (size_t)i0 * DM);
        for (int t = tid; t < KVROWS * DM / 4; t += 128) {
            ((float4*)xS)[t] = sx[t];
            ((float4*)sS)[t] = ss[t];
        }
    }
    __syncthreads();
    if (tid >= 96) return;
    const int m = tid >> 5;        // 0: Ka, 1: Kr, 2: SV
    const int p = tid & 31;
    const float2* __restrict__ w2 = (const float2*)(m == 0 ? wka : (m == 1 ? wkr : wv)); // 32 pairs/row
    const float* __restrict__ src = (m == 2) ? sS : xS;
    float ae[KVROWS], ao[KVROWS];
#pragma unroll
    for (int r = 0; r < KVROWS; ++r) { ae[r] = 0.f; ao[r] = 0.f; }
    for (int k = 0; k < DM; ++k) {
        float2 w = w2[k * 32 + p];
#pragma unroll
        for (int r = 0; r < KVROWS; ++r) {
            float xv = src[r * DM + k];
            ae[r] = fmaf(xv, w.x, ae[r]);
            ao[r] = fmaf(xv, w.y, ao[r]);
        }
    }
    float* __restrict__ dst = (m == 0 ? Ka : (m == 1 ? Kr : SV));
#pragma unroll
    for (int r = 0; r < KVROWS; ++r) {
        float oe = ae[r], oo = ao[r];
        if (m == 0) {
            float c = fcos[(i0 + r) * NPAIR + p];
            float s = fsin[(i0 + r) * NPAIR + p];
            oe = ae[r] * c - ao[r] * s;
            oo = ae[r] * s + ao[r] * c;
        }
        dst[(i0 + r) * HD + 2 * p] = oe;
        dst[(i0 + r) * HD + 2 * p + 1] = oo;
    }
}

// ---------------- rel scores: rel[h,i,j] = scale * Qr[i,h,:]·Kr[j,:]  (full, no mask) ----
__global__ __launch_bounds__(256) void k_rel(
    const float* __restrict__ Qr, const float* __restrict__ Kr, float* __restrict__ relout)
{
    __shared__ float QS[64][65];
    __shared__ float KS[64][65];
    const int j0 = blockIdx.x * 64, i0 = blockIdx.y * 64, h = blockIdx.z;
    const int tid = threadIdx.x;
    for (int t = tid; t < 64 * 64; t += 256) {
        int r = t >> 6, c = t & 63;
        QS[r][c] = Qr[(size_t)(i0 + r) * DM + h * HD + c];
        KS[r][c] = Kr[(j0 + r) * HD + c];
    }
    __syncthreads();
    const int ti = tid & 15, tj = tid >> 4;
    float acc[4][4] = {};
    for (int d = 0; d < HD; ++d) {
        float qv[4], kv[4];
#pragma unroll
        for (int a = 0; a < 4; ++a) qv[a] = QS[ti * 4 + a][d];
#pragma unroll
        for (int b = 0; b < 4; ++b) kv[b] = KS[tj * 4 + b][d];
#pragma unroll
        for (int a = 0; a < 4; ++a)
#pragma unroll
            for (int b = 0; b < 4; ++b) acc[a][b] = fmaf(qv[a], kv[b], acc[a][b]);
    }
#pragma unroll
    for (int a = 0; a < 4; ++a) {
        float4 w = make_float4(acc[a][0] * SCALE_F, acc[a][1] * SCALE_F,
                               acc[a][2] * SCALE_F, acc[a][3] * SCALE_F);
        *(float4*)&relout[(size_t)(h * LQ + i0 + ti * 4 + a) * LQ + j0 + tj * 4] = w;
    }
}

// ---------------- pass 1: causal softmax stats (row max M, row sum L) ----------------
__global__ __launch_bounds__(256) void k_stats(
    const float* __restrict__ Qa, const float* __restrict__ Ka,
    float* __restrict__ Mrow, float* __restrict__ Lrow)
{
    __shared__ float QS[64][65];
    __shared__ float KS[64][65];
    __shared__ float redM[64][17];
    __shared__ float redL[64][17];
    const int it = blockIdx.x, h = blockIdx.y;
    const int i0 = it * 64;
    const int tid = threadIdx.x;
    for (int t = tid; t < 64 * 64; t += 256) {
        int r = t >> 6, c = t & 63;
        QS[r][c] = Qa[(size_t)(i0 + r) * DM + h * HD + c];
    }
    const int ti = tid & 15, tj = tid >> 4;
    float m_[4], l_[4];
#pragma unroll
    for (int a = 0; a < 4; ++a) { m_[a] = -INFINITY; l_[a] = 0.f; }
    for (int jt = 0; jt <= it; ++jt) {
        const int j0 = jt * 64;
        __syncthreads();
        for (int t = tid; t < 64 * 64; t += 256) {
            int r = t >> 6, c = t & 63;
            KS[r][c] = Ka[(j0 + r) * HD + c];
        }
        __syncthreads();
        float s[4][4] = {};
        for (int d = 0; d < HD; ++d) {
            float qv[4], kv[4];
#pragma unroll
            for (int a = 0; a < 4; ++a) qv[a] = QS[ti * 4 + a][d];
#pragma unroll
            for (int b = 0; b < 4; ++b) kv[b] = KS[tj * 4 + b][d];
#pragma unroll
            for (int a = 0; a < 4; ++a)
#pragma unroll
                for (int b = 0; b < 4; ++b) s[a][b] = fmaf(qv[a], kv[b], s[a][b]);
        }
#pragma unroll
        for (int a = 0; a < 4; ++a) {
            const int i = i0 + ti * 4 + a;
            float mx = m_[a];
#pragma unroll
            for (int b = 0; b < 4; ++b) {
                int j = j0 + tj * 4 + b;
                if (j <= i) mx = fmaxf(mx, s[a][b] * SCALE_F);
            }
            if (mx > m_[a]) {
                l_[a] *= __expf(m_[a] - mx);
                m_[a] = mx;
            }
#pragma unroll
            for (int b = 0; b < 4; ++b) {
                int j = j0 + tj * 4 + b;
                if (j <= i) l_[a] += __expf(s[a][b] * SCALE_F - m_[a]);
            }
        }
    }
    __syncthreads();
#pragma unroll
    for (int a = 0; a < 4; ++a) {
        redM[ti * 4 + a][tj] = m_[a];
        redL[ti * 4 + a][tj] = l_[a];
    }
    __syncthreads();
    if (tid < 64) {
        float M = -INFINITY, Lsum = 0.f;
        for (int t = 0; t < 16; ++t) M = fmaxf(M, redM[tid][t]);
        for (int t = 0; t < 16; ++t) {
            float lk = redL[tid][t];
            if (lk > 0.f) Lsum += lk * __expf(redM[tid][t] - M);
        }
        Mrow[h * LQ + i0 + tid] = M;
        Lrow[h * LQ + i0 + tid] = Lsum;
    }
}

// ---------------- pass 2: write attn (f32), p = attn*rel, O = p @ SV ----------------
__global__ __launch_bounds__(256) void k_attn_out(
    const float* __restrict__ Qa, const float* __restrict__ Ka, const float* __restrict__ SV,
    const float* __restrict__ Mrow, const float* __restrict__ Lrow,
    const float* __restrict__ relin, float* __restrict__ attnout, float* __restrict__ OutH)
{
    __shared__ float QS[64][65];
    __shared__ float KS[64][65];    // reused as pS after scores are consumed
    __shared__ float SVS[64][65];
    float (*pS)[65] = KS;
    const int it = blockIdx.x, h = blockIdx.y;
    const int i0 = it * 64;
    const int tid = threadIdx.x;
    for (int t = tid; t < 64 * 64; t += 256) {
        int r = t >> 6, c = t & 63;
        QS[r][c] = Qa[(size_t)(i0 + r) * DM + h * HD + c];
    }
    const int ti = tid & 15, tj = tid >> 4;
    float M[4], Linv[4];
#pragma unroll
    for (int a = 0; a < 4; ++a) {
        int i = i0 + ti * 4 + a;
        M[a] = Mrow[h * LQ + i];
        Linv[a] = 1.0f / Lrow[h * LQ + i];
    }
    float oacc[4][4] = {};
    for (int jt = 0; jt <= it; ++jt) {
        const int j0 = jt * 64;
        __syncthreads();  // prior PV (reads pS/SVS) done before reload
        for (int t = tid; t < 64 * 64; t += 256) {
            int r = t >> 6, c = t & 63;
            KS[r][c] = Ka[(j0 + r) * HD + c];
            SVS[r][c] = SV[(j0 + r) * HD + c];
        }
        __syncthreads();
        float s[4][4] = {};
        for (int d = 0; d < HD; ++d) {
            float qv[4], kv[4];
#pragma unroll
            for (int a = 0; a < 4; ++a) qv[a] = QS[ti * 4 + a][d];
#pragma unroll
            for (int b = 0; b < 4; ++b) kv[b] = KS[tj * 4 + b][d];
#pragma unroll
            for (int a = 0; a < 4; ++a)
#pragma unroll
                for (int b = 0; b < 4; ++b) s[a][b] = fmaf(qv[a], kv[b], s[a][b]);
        }
        __syncthreads();  // scores done; KS region becomes pS
#pragma unroll
        for (int a = 0; a < 4; ++a) {
            const int i = i0 + ti * 4 + a;
            const int jb = j0 + tj * 4;
            float4 rv = *(const float4*)&relin[(size_t)(h * LQ + i) * LQ + jb];
            float rl[4] = { rv.x, rv.y, rv.z, rv.w };
            float av[4];
#pragma unroll
            for (int b = 0; b < 4; ++b) {
                int j = jb + b;
                float sc = s[a][b] * SCALE_F;
                av[b] = (j <= i) ? __expf(sc - M[a]) * Linv[a] : 0.f;
                pS[ti * 4 + a][tj * 4 + b] = av[b] * rl[b];
            }
            *(float4*)&attnout[(size_t)(h * LQ + i) * LQ + jb] =
                make_float4(av[0], av[1], av[2], av[3]);
        }
        __syncthreads();  // pS complete
        for (int j = 0; j < 64; ++j) {
            float pv[4], sv4[4];
#pragma unroll
            for (int a = 0; a < 4; ++a) pv[a] = pS[ti * 4 + a][j];
#pragma unroll
            for (int dd = 0; dd < 4; ++dd) sv4[dd] = SVS[j][tj * 4 + dd];
#pragma unroll
            for (int a = 0; a < 4; ++a)
#pragma unroll
                for (int dd = 0; dd < 4; ++dd)
                    oacc[a][dd] = fmaf(pv[a], sv4[dd], oacc[a][dd]);
        }
    }
    // zero-fill strictly-upper tiles of attn (harness poisons d_out before each launch)
    const int zstart = (it + 1) * 64;
    if (zstart < LQ) {
        const int per_row = (LQ - zstart) >> 2;   // float4 units per row
        const int total = 64 * per_row;
        float4 z = make_float4(0.f, 0.f, 0.f, 0.f);
        for (int idx = tid; idx < total; idx += 256) {
            int r = idx / per_row, c = idx - r * per_row;
            *(float4*)&attnout[(size_t)(h * LQ + i0 + r) * LQ + zstart + c * 4] = z;
        }
    }
#pragma unroll
    for (int a = 0; a < 4; ++a) {
        float4 v = make_float4(oacc[a][0], oacc[a][1], oacc[a][2], oacc[a][3]);
        *(float4*)&OutH[(size_t)(i0 + ti * 4 + a) * DM + h * HD + tj * 4] = v;
    }
}

// ---------------- final projection: out = OutH @ wo ----------------
__global__ __launch_bounds__(256) void k_outproj(
    const float* __restrict__ OutH, const float* __restrict__ wo, float* __restrict__ outp)
{
    __shared__ float AS[64][65];
    __shared__ float BS[64][65];
    const int n0 = blockIdx.x * 64, i0 = blockIdx.y * 64;
    const int tid = threadIdx.x;
    const int ti = tid & 15, tj = tid >> 4;
    float acc[4][4] = {};
    for (int kt = 0; kt < DM / 64; ++kt) {
        const int k0 = kt * 64;
        __syncthreads();
        for (int t = tid; t < 64 * 64; t += 256) {
            int r = t >> 6, c = t & 63;
            AS[r][c] = OutH[(size_t)(i0 + r) * DM + k0 + c];
            BS[r][c] = wo[(size_t)(k0 + r) * DM + n0 + c];
        }
        __syncthreads();
        for (int kk = 0; kk < 64; ++kk) {
            float av[4], bv[4];
#pragma unroll
            for (int a = 0; a < 4; ++a) av[a] = AS[ti * 4 + a][kk];
#pragma unroll
            for (int b = 0; b < 4; ++b) bv[b] = BS[kk][tj * 4 + b];
#pragma unroll
            for (int a = 0; a < 4; ++a)
#pragma unroll
                for (int b = 0; b < 4; ++b) acc[a][b] = fmaf(av[a], bv[b], acc[a][b]);
        }
    }
#pragma unroll
    for (int a = 0; a < 4; ++a) {
        float4 v = make_float4(acc[a][0], acc[a][1], acc[a][2], acc[a][3]);
        *(float4*)&outp[(size_t)(i0 + ti * 4 + a) * DM + n0 + tj * 4] = v;
    }
}

extern "C" void kernel_launch(void* const* d_in, const int* in_sizes, int n_in,
                              void* d_out, int out_size, void* d_ws, size_t ws_size,
                              hipStream_t stream)
{
    const float* x       = (const float*)d_in[0];
    const float* symbols = (const float*)d_in[1];
    const float* fcos    = (const float*)d_in[2];
    const float* fsin    = (const float*)d_in[3];
    const float* wqa     = (const float*)d_in[4];
    const float* wka     = (const float*)d_in[5];
    const float* wqr     = (const float*)d_in[6];
    const float* wkr     = (const float*)d_in[7];
    const float* wv      = (const float*)d_in[8];
    const float* wo      = (const float*)d_in[9];

    float* out_main = (float*)d_out;                     // (2048, 1024) f32
    float* out_attn = out_main + (size_t)LQ * DM;        // (16, 2048, 2048) f32
    float* out_rel  = out_attn + (size_t)NH * LQ * LQ;   // (16, 2048, 2048) f32

    float* ws   = (float*)d_ws;
    float* Qa   = ws;                       // 2048*1024
    float* Qr   = Qa + (size_t)LQ * DM;     // 2048*1024
    float* Ka   = Qr + (size_t)LQ * DM;     // 2048*64
    float* Kr   = Ka + (size_t)LQ * HD;
    float* SV   = Kr + (size_t)LQ * HD;
    float* Mrow = SV + (size_t)LQ * HD;     // 16*2048
    float* Lrow = Mrow + (size_t)NH * LQ;
    float* OutH = Lrow + (size_t)NH * LQ;   // 2048*1024

    k_proj_q<<<dim3((LQ / QROWS) * 4), 256, 0, stream>>>(x, wqa, wqr, fcos, fsin, Qa, Qr);
    k_proj_kv<<<dim3(LQ / KVROWS), 128, 0, stream>>>(x, symbols, wka, wkr, wv, fcos, fsin, Ka, Kr, SV);
    k_rel<<<dim3(32, 32, 16), 256, 0, stream>>>(Qr, Kr, out_rel);
    k_stats<<<dim3(32, 16), 256, 0, stream>>>(Qa, Ka, Mrow, Lrow);
    k_attn_out<<<dim3(32, 16), 256, 0, stream>>>(Qa, Ka, SV, Mrow, Lrow, out_rel, out_attn, OutH);
    k_outproj<<<dim3(16, 32), 256, 0, stream>>>(OutH, wo, out_main);
}